// Round 1
// baseline (101.075 us; speedup 1.0000x reference)
//
#include <hip/hip_runtime.h>

#define D_  128
#define B_  2
#define N1_ 500
#define N2_ 800

// ---------------------------------------------------------------------------
// Prologue: P1[b,n,f] = sum_k h1[b,n,k]*W1[k,f] + b1[f]
//           P2[b,m,f] = sum_k h2[b,m,k]*W1[D+k,f]
// One block = 16 rows. Threads: c = tid&127 (output col), rg = tid>>7 (row grp).
// ---------------------------------------------------------------------------
__global__ __launch_bounds__(256) void proj_kernel(
    const float* __restrict__ h1, const float* __restrict__ h2,
    const float* __restrict__ W1, const float* __restrict__ b1,
    float* __restrict__ P1, float* __restrict__ P2)
{
    __shared__ float hs[16][128];
    const int NB1 = (B_ * N1_ + 15) / 16;   // 63 blocks for P1 (1000 rows)
    bool isP1 = (int)blockIdx.x < NB1;
    int r0 = (isP1 ? (int)blockIdx.x : (int)blockIdx.x - NB1) * 16;
    int R  = isP1 ? B_ * N1_ : B_ * N2_;
    const float* __restrict__ src = isP1 ? h1 : h2;
    float* __restrict__ dst = isP1 ? P1 : P2;
    const int koff = isP1 ? 0 : D_;

    int tid = threadIdx.x;
    // stage 16 rows of src (coalesced float4)
    #pragma unroll
    for (int j = 0; j < 2; ++j) {
        int fi  = tid + j * 256;       // 512 float4s = 16x128 floats
        int row = fi >> 5;
        int c4  = (fi & 31) * 4;
        float4 v = make_float4(0.f, 0.f, 0.f, 0.f);
        int r = r0 + row;
        if (r < R) v = *reinterpret_cast<const float4*>(&src[(size_t)r * D_ + c4]);
        *reinterpret_cast<float4*>(&hs[row][c4]) = v;
    }
    __syncthreads();

    int c  = tid & 127;
    int rg = tid >> 7;
    const float* __restrict__ Wc = W1 + (size_t)koff * D_ + c;
    float acc[8];
    float binit = isP1 ? b1[c] : 0.f;
    #pragma unroll
    for (int i = 0; i < 8; ++i) acc[i] = binit;

    for (int k4 = 0; k4 < D_; k4 += 4) {
        float w0 = Wc[(k4 + 0) * D_];
        float w1 = Wc[(k4 + 1) * D_];
        float w2 = Wc[(k4 + 2) * D_];
        float w3 = Wc[(k4 + 3) * D_];
        #pragma unroll
        for (int i = 0; i < 8; ++i) {
            float4 h = *reinterpret_cast<const float4*>(&hs[rg * 8 + i][k4]);
            acc[i] = fmaf(h.x, w0, acc[i]);
            acc[i] = fmaf(h.y, w1, acc[i]);
            acc[i] = fmaf(h.z, w2, acc[i]);
            acc[i] = fmaf(h.w, w3, acc[i]);
        }
    }
    #pragma unroll
    for (int i = 0; i < 8; ++i) {
        int r = r0 + rg * 8 + i;
        if (r < R) dst[(size_t)r * D_ + c] = acc[i];
    }
}

// ---------------------------------------------------------------------------
// Pair kernel: block tile = 16 n x 64 m. 4 waves; wave w owns n-rows [4w,4w+4),
// lane = m offset. P2 tile in LDS with +4 pad (stride 132 words) so the
// per-lane stride-528B ds_read_b128 tiles all 32 banks minimally. P1/W2 reads
// are wave-uniform broadcasts (conflict-free). 3 VALU insts per (n,m,d).
// ---------------------------------------------------------------------------
__global__ __launch_bounds__(256) void pair_kernel(
    const int* __restrict__ S1, const int* __restrict__ S2,
    const float* __restrict__ contact,
    const float* __restrict__ P1, const float* __restrict__ P2,
    const float* __restrict__ W2, const float* __restrict__ b2,
    float* __restrict__ out)
{
    const int NT = 16, MT = 64;
    const int nTn = (N1_ + NT - 1) / NT;    // 32
    const int nTm = (N2_ + MT - 1) / MT;    // 13
    int bid = blockIdx.x;
    int tb  = bid / (nTn * nTm);
    int rem = bid % (nTn * nTm);
    int tn  = rem / nTm;
    int tm  = rem % nTm;
    int n0 = tn * NT, m0 = tm * MT;
    int tid = threadIdx.x, lane = tid & 63, wave = tid >> 6;

    __shared__ float p2s[64 * 132];   // padded stride 132 (16B-aligned rows)
    __shared__ float p1s[16 * 128];
    __shared__ float w2s[128];
    __shared__ float m1s[16];

    // stage P2 tile (contiguous 32KB when full; guarded tail)
    const float* __restrict__ P2b = P2 + ((size_t)tb * N2_ + m0) * D_;
    #pragma unroll
    for (int j = 0; j < 8; ++j) {
        int fi  = tid + j * 256;      // 2048 float4s = 64x128 floats
        int row = fi >> 5;
        int c4  = (fi & 31) * 4;
        float4 v = make_float4(0.f, 0.f, 0.f, 0.f);
        if (m0 + row < N2_) v = *reinterpret_cast<const float4*>(&P2b[row * D_ + c4]);
        *reinterpret_cast<float4*>(&p2s[row * 132 + c4]) = v;
    }
    // stage P1 tile
    const float* __restrict__ P1b = P1 + ((size_t)tb * N1_ + n0) * D_;
    #pragma unroll
    for (int j = 0; j < 2; ++j) {
        int fi  = tid + j * 256;
        int row = fi >> 5;
        int c4  = (fi & 31) * 4;
        float4 v = make_float4(0.f, 0.f, 0.f, 0.f);
        if (n0 + row < N1_) v = *reinterpret_cast<const float4*>(&P1b[row * D_ + c4]);
        *reinterpret_cast<float4*>(&p1s[row * 128 + c4]) = v;
    }
    if (tid < 32)
        *reinterpret_cast<float4*>(&w2s[tid * 4]) =
            *reinterpret_cast<const float4*>(&W2[tid * 4]);
    if (tid >= 64 && tid < 80) {
        int i = tid - 64;
        m1s[i] = (n0 + i < N1_ && S1[tb * N1_ + n0 + i] != 0) ? 1.f : 0.f;
    }
    __syncthreads();

    int nw = wave * 4;
    float acc[4] = {0.f, 0.f, 0.f, 0.f};
    const float* p2p = &p2s[lane * 132];
    const float* p1p = &p1s[nw * 128];

    #pragma unroll 8
    for (int d = 0; d < D_; d += 4) {
        float4 q2 = *reinterpret_cast<const float4*>(&p2p[d]);
        float4 w  = *reinterpret_cast<const float4*>(&w2s[d]);
        #pragma unroll
        for (int i = 0; i < 4; ++i) {
            float4 q1 = *reinterpret_cast<const float4*>(&p1p[i * 128 + d]);
            acc[i] = fmaf(fmaxf(q1.x + q2.x, 0.f), w.x, acc[i]);
            acc[i] = fmaf(fmaxf(q1.y + q2.y, 0.f), w.y, acc[i]);
            acc[i] = fmaf(fmaxf(q1.z + q2.z, 0.f), w.z, acc[i]);
            acc[i] = fmaf(fmaxf(q1.w + q2.w, 0.f), w.w, acc[i]);
        }
    }

    // fused epilogue: pred (unmasked), y_contact, mask — all coalesced along m
    int m = m0 + lane;
    float m2 = (m < N2_ && S2[tb * N2_ + m] != 0) ? 1.f : 0.f;
    float bias2 = b2[0];
    const size_t NN  = (size_t)N1_ * N2_;   // 400000
    const size_t TOT = (size_t)B_ * NN;     // 800000
    #pragma unroll
    for (int i = 0; i < 4; ++i) {
        int n = n0 + nw + i;
        if (n < N1_ && m < N2_) {
            float mk  = m1s[nw + i] * m2;
            size_t off = (size_t)tb * NN + (size_t)n * N2_ + m;
            float cv  = contact[off];
            out[off]           = acc[i] + bias2;
            out[TOT + off]     = (cv < 0.5f) ? mk : 0.f;
            out[2 * TOT + off] = mk;
        }
    }
}

extern "C" void kernel_launch(void* const* d_in, const int* in_sizes, int n_in,
                              void* d_out, int out_size, void* d_ws, size_t ws_size,
                              hipStream_t stream) {
    const int*   S1      = (const int*)d_in[0];
    const int*   S2      = (const int*)d_in[1];
    const float* h1      = (const float*)d_in[2];
    const float* h2      = (const float*)d_in[3];
    const float* contact = (const float*)d_in[4];
    const float* W1      = (const float*)d_in[5];
    const float* b1      = (const float*)d_in[6];
    const float* W2      = (const float*)d_in[7];
    const float* b2      = (const float*)d_in[8];
    float* out = (float*)d_out;

    float* P1 = (float*)d_ws;                         // B*N1*D floats
    float* P2 = P1 + (size_t)B_ * N1_ * D_;           // B*N2*D floats

    const int projBlocks = (B_ * N1_ + 15) / 16 + (B_ * N2_) / 16;  // 63 + 100
    proj_kernel<<<projBlocks, 256, 0, stream>>>(h1, h2, W1, b1, P1, P2);

    const int pairBlocks = B_ * ((N1_ + 15) / 16) * ((N2_ + 63) / 64); // 832
    pair_kernel<<<pairBlocks, 256, 0, stream>>>(S1, S2, contact, P1, P2, W2, b2, out);
}

// Round 2
// 100.927 us; speedup vs baseline: 1.0015x; 1.0015x over previous
//
#include <hip/hip_runtime.h>

#define D_  128
#define B_  2
#define N1_ 500
#define N2_ 800

// ---------------------------------------------------------------------------
// Prologue: P1[b,n,f] = sum_k h1[b,n,k]*W1[k,f] + b1[f]
//           P2[b,m,f] = sum_k h2[b,m,k]*W1[D+k,f]
// One block = 16 rows. Threads: c = tid&127 (output col), rg = tid>>7 (row grp).
// W1 column loads are coalesced across the 128 c-lanes; h rows broadcast
// from LDS.
// ---------------------------------------------------------------------------
__global__ __launch_bounds__(256) void proj_kernel(
    const float* __restrict__ h1, const float* __restrict__ h2,
    const float* __restrict__ W1, const float* __restrict__ b1,
    float* __restrict__ P1, float* __restrict__ P2)
{
    __shared__ float hs[16][128];
    const int NB1 = (B_ * N1_ + 15) / 16;   // 63 blocks for P1 (1000 rows)
    bool isP1 = (int)blockIdx.x < NB1;
    int r0 = (isP1 ? (int)blockIdx.x : (int)blockIdx.x - NB1) * 16;
    int R  = isP1 ? B_ * N1_ : B_ * N2_;
    const float* __restrict__ src = isP1 ? h1 : h2;
    float* __restrict__ dst = isP1 ? P1 : P2;
    const int koff = isP1 ? 0 : D_;

    int tid = threadIdx.x;
    #pragma unroll
    for (int j = 0; j < 2; ++j) {
        int fi  = tid + j * 256;       // 512 float4s = 16x128 floats
        int row = fi >> 5;
        int c4  = (fi & 31) * 4;
        float4 v = make_float4(0.f, 0.f, 0.f, 0.f);
        int r = r0 + row;
        if (r < R) v = *reinterpret_cast<const float4*>(&src[(size_t)r * D_ + c4]);
        *reinterpret_cast<float4*>(&hs[row][c4]) = v;
    }
    __syncthreads();

    int c  = tid & 127;
    int rg = tid >> 7;
    const float* __restrict__ Wc = W1 + (size_t)koff * D_ + c;
    float acc[8];
    float binit = isP1 ? b1[c] : 0.f;
    #pragma unroll
    for (int i = 0; i < 8; ++i) acc[i] = binit;

    for (int k4 = 0; k4 < D_; k4 += 4) {
        float w0 = Wc[(k4 + 0) * D_];
        float w1 = Wc[(k4 + 1) * D_];
        float w2 = Wc[(k4 + 2) * D_];
        float w3 = Wc[(k4 + 3) * D_];
        #pragma unroll
        for (int i = 0; i < 8; ++i) {
            float4 h = *reinterpret_cast<const float4*>(&hs[rg * 8 + i][k4]);
            acc[i] = fmaf(h.x, w0, acc[i]);
            acc[i] = fmaf(h.y, w1, acc[i]);
            acc[i] = fmaf(h.z, w2, acc[i]);
            acc[i] = fmaf(h.w, w3, acc[i]);
        }
    }
    #pragma unroll
    for (int i = 0; i < 8; ++i) {
        int r = r0 + rg * 8 + i;
        if (r < R) dst[(size_t)r * D_ + c] = acc[i];
    }
}

// ---------------------------------------------------------------------------
// Pair kernel: block tile = 16 n x 128 m. 4 waves; wave w owns n-rows
// [4w,4w+4); each lane owns TWO m columns (lane, lane+64) so every broadcast
// p1/w2 LDS read serves 8 outputs instead of 4 (28 LDS reads/output vs 48).
// p2 rows padded to stride 132 (8-lanes-per-bank-group on ds_read_b128 = the
// structural 8-phase floor for 1KB/wave-inst). LDS 76KB -> 2 blocks/CU.
// ---------------------------------------------------------------------------
__global__ __launch_bounds__(256) void pair_kernel(
    const int* __restrict__ S1, const int* __restrict__ S2,
    const float* __restrict__ contact,
    const float* __restrict__ P1, const float* __restrict__ P2,
    const float* __restrict__ W2, const float* __restrict__ b2,
    float* __restrict__ out)
{
    const int NT = 16, MT = 128;
    const int nTn = (N1_ + NT - 1) / NT;    // 32
    const int nTm = (N2_ + MT - 1) / MT;    // 7
    int bid = blockIdx.x;
    int tb  = bid / (nTn * nTm);
    int rem = bid % (nTn * nTm);
    int tn  = rem / nTm;
    int tm  = rem % nTm;
    int n0 = tn * NT, m0 = tm * MT;
    int tid = threadIdx.x, lane = tid & 63, wave = tid >> 6;

    __shared__ float p2s[128 * 132];  // 67.6 KB, padded stride
    __shared__ float p1s[16 * 128];   // 8 KB
    __shared__ float w2s[128];
    __shared__ float m1s[16];

    // stage P2 tile (128 rows x 128 floats; guarded tail rows -> 0)
    const float* __restrict__ P2b = P2 + ((size_t)tb * N2_ + m0) * D_;
    #pragma unroll
    for (int j = 0; j < 16; ++j) {
        int fi  = tid + j * 256;      // 4096 float4s
        int row = fi >> 5;
        int c4  = (fi & 31) * 4;
        float4 v = make_float4(0.f, 0.f, 0.f, 0.f);
        if (m0 + row < N2_) v = *reinterpret_cast<const float4*>(&P2b[row * D_ + c4]);
        *reinterpret_cast<float4*>(&p2s[row * 132 + c4]) = v;
    }
    // stage P1 tile
    const float* __restrict__ P1b = P1 + ((size_t)tb * N1_ + n0) * D_;
    #pragma unroll
    for (int j = 0; j < 2; ++j) {
        int fi  = tid + j * 256;
        int row = fi >> 5;
        int c4  = (fi & 31) * 4;
        float4 v = make_float4(0.f, 0.f, 0.f, 0.f);
        if (n0 + row < N1_) v = *reinterpret_cast<const float4*>(&P1b[row * D_ + c4]);
        *reinterpret_cast<float4*>(&p1s[row * 128 + c4]) = v;
    }
    if (tid < 32)
        *reinterpret_cast<float4*>(&w2s[tid * 4]) =
            *reinterpret_cast<const float4*>(&W2[tid * 4]);
    if (tid >= 64 && tid < 80) {
        int i = tid - 64;
        m1s[i] = (n0 + i < N1_ && S1[tb * N1_ + n0 + i] != 0) ? 1.f : 0.f;
    }
    __syncthreads();

    int nw = wave * 4;
    float acc0[4] = {0.f, 0.f, 0.f, 0.f};
    float acc1[4] = {0.f, 0.f, 0.f, 0.f};
    const float* p2a = &p2s[lane * 132];
    const float* p2b = &p2s[(lane + 64) * 132];
    const float* p1p = &p1s[nw * 128];

    #pragma unroll 4
    for (int d = 0; d < D_; d += 4) {
        float4 qa = *reinterpret_cast<const float4*>(&p2a[d]);
        float4 qb = *reinterpret_cast<const float4*>(&p2b[d]);
        float4 w  = *reinterpret_cast<const float4*>(&w2s[d]);
        #pragma unroll
        for (int i = 0; i < 4; ++i) {
            float4 q1 = *reinterpret_cast<const float4*>(&p1p[i * 128 + d]);
            acc0[i] = fmaf(fmaxf(q1.x + qa.x, 0.f), w.x, acc0[i]);
            acc0[i] = fmaf(fmaxf(q1.y + qa.y, 0.f), w.y, acc0[i]);
            acc0[i] = fmaf(fmaxf(q1.z + qa.z, 0.f), w.z, acc0[i]);
            acc0[i] = fmaf(fmaxf(q1.w + qa.w, 0.f), w.w, acc0[i]);
            acc1[i] = fmaf(fmaxf(q1.x + qb.x, 0.f), w.x, acc1[i]);
            acc1[i] = fmaf(fmaxf(q1.y + qb.y, 0.f), w.y, acc1[i]);
            acc1[i] = fmaf(fmaxf(q1.z + qb.z, 0.f), w.z, acc1[i]);
            acc1[i] = fmaf(fmaxf(q1.w + qb.w, 0.f), w.w, acc1[i]);
        }
    }

    // fused epilogue: pred (unmasked), y_contact, mask — coalesced along m
    int mA = m0 + lane;
    int mB = m0 + 64 + lane;
    float m2A = (mA < N2_ && S2[tb * N2_ + mA] != 0) ? 1.f : 0.f;
    float m2B = (mB < N2_ && S2[tb * N2_ + mB] != 0) ? 1.f : 0.f;
    float bias2 = b2[0];
    const size_t NN  = (size_t)N1_ * N2_;   // 400000
    const size_t TOT = (size_t)B_ * NN;     // 800000
    #pragma unroll
    for (int i = 0; i < 4; ++i) {
        int n = n0 + nw + i;
        if (n >= N1_) break;
        float m1v = m1s[nw + i];
        size_t rowoff = (size_t)tb * NN + (size_t)n * N2_;
        if (mA < N2_) {
            float mk = m1v * m2A;
            size_t off = rowoff + mA;
            float cv = contact[off];
            out[off]           = acc0[i] + bias2;
            out[TOT + off]     = (cv < 0.5f) ? mk : 0.f;
            out[2 * TOT + off] = mk;
        }
        if (mB < N2_) {
            float mk = m1v * m2B;
            size_t off = rowoff + mB;
            float cv = contact[off];
            out[off]           = acc1[i] + bias2;
            out[TOT + off]     = (cv < 0.5f) ? mk : 0.f;
            out[2 * TOT + off] = mk;
        }
    }
}

extern "C" void kernel_launch(void* const* d_in, const int* in_sizes, int n_in,
                              void* d_out, int out_size, void* d_ws, size_t ws_size,
                              hipStream_t stream) {
    const int*   S1      = (const int*)d_in[0];
    const int*   S2      = (const int*)d_in[1];
    const float* h1      = (const float*)d_in[2];
    const float* h2      = (const float*)d_in[3];
    const float* contact = (const float*)d_in[4];
    const float* W1      = (const float*)d_in[5];
    const float* b1      = (const float*)d_in[6];
    const float* W2      = (const float*)d_in[7];
    const float* b2      = (const float*)d_in[8];
    float* out = (float*)d_out;

    float* P1 = (float*)d_ws;                         // B*N1*D floats
    float* P2 = P1 + (size_t)B_ * N1_ * D_;           // B*N2*D floats

    const int projBlocks = (B_ * N1_ + 15) / 16 + (B_ * N2_) / 16;  // 63 + 100
    proj_kernel<<<projBlocks, 256, 0, stream>>>(h1, h2, W1, b1, P1, P2);

    const int pairBlocks = B_ * ((N1_ + 15) / 16) * ((N2_ + 127) / 128); // 448
    pair_kernel<<<pairBlocks, 256, 0, stream>>>(S1, S2, contact, P1, P2, W2, b2, out);
}

// Round 3
// 99.830 us; speedup vs baseline: 1.0125x; 1.0110x over previous
//
#include <hip/hip_runtime.h>

#define D_  128
#define B_  2
#define N1_ 500
#define N2_ 800

// ---------------------------------------------------------------------------
// Prologue: P1[b,n,f] = sum_k h1[b,n,k]*W1[k,f] + b1[f]
//           P2[b,m,f] = sum_k h2[b,m,k]*W1[D+k,f]
// 8 rows/block (325 blocks -> 1.3 blocks/CU) + k-loop unroll 4 so 16 W1
// loads are in flight: proj was latency-bound (4 L2-hit loads / iter, no
// unroll, 1 block/CU). c = tid&127 (output col, coalesced W1 column loads),
// rg = tid>>7 (row group of 4).
// ---------------------------------------------------------------------------
__global__ __launch_bounds__(256) void proj_kernel(
    const float* __restrict__ h1, const float* __restrict__ h2,
    const float* __restrict__ W1, const float* __restrict__ b1,
    float* __restrict__ P1, float* __restrict__ P2)
{
    __shared__ float hs[8][128];
    const int NB1 = (B_ * N1_ + 7) / 8;   // 125 blocks for P1 (1000 rows)
    bool isP1 = (int)blockIdx.x < NB1;
    int r0 = (isP1 ? (int)blockIdx.x : (int)blockIdx.x - NB1) * 8;
    int R  = isP1 ? B_ * N1_ : B_ * N2_;
    const float* __restrict__ src = isP1 ? h1 : h2;
    float* __restrict__ dst = isP1 ? P1 : P2;
    const int koff = isP1 ? 0 : D_;

    int tid = threadIdx.x;
    // stage 8 rows (256 float4 = one per thread, coalesced)
    {
        int row = tid >> 5;
        int c4  = (tid & 31) * 4;
        float4 v = make_float4(0.f, 0.f, 0.f, 0.f);
        int r = r0 + row;
        if (r < R) v = *reinterpret_cast<const float4*>(&src[(size_t)r * D_ + c4]);
        *reinterpret_cast<float4*>(&hs[row][c4]) = v;
    }
    __syncthreads();

    int c  = tid & 127;
    int rg = tid >> 7;
    const float* __restrict__ Wc = W1 + (size_t)koff * D_ + c;
    float acc[4];
    float binit = isP1 ? b1[c] : 0.f;
    #pragma unroll
    for (int i = 0; i < 4; ++i) acc[i] = binit;

    #pragma unroll 4
    for (int k4 = 0; k4 < D_; k4 += 4) {
        float w0 = Wc[(k4 + 0) * D_];
        float w1 = Wc[(k4 + 1) * D_];
        float w2 = Wc[(k4 + 2) * D_];
        float w3 = Wc[(k4 + 3) * D_];
        #pragma unroll
        for (int i = 0; i < 4; ++i) {
            float4 h = *reinterpret_cast<const float4*>(&hs[rg * 4 + i][k4]);
            acc[i] = fmaf(h.x, w0, acc[i]);
            acc[i] = fmaf(h.y, w1, acc[i]);
            acc[i] = fmaf(h.z, w2, acc[i]);
            acc[i] = fmaf(h.w, w3, acc[i]);
        }
    }
    #pragma unroll
    for (int i = 0; i < 4; ++i) {
        int r = r0 + rg * 4 + i;
        if (r < R) dst[(size_t)r * D_ + c] = acc[i];
    }
}

// ---------------------------------------------------------------------------
// Pair kernel: block tile = 16 n x 128 m. 4 waves; wave w owns n-rows
// [4w,4w+4); each lane owns TWO m columns (lane, lane+64). Tail m-tile
// (m0=768, only 32 real columns) takes a wave-uniform single-column path
// (skips qb/acc1 entirely) instead of computing 75% garbage.
// p2 rows padded to stride 132: b128 reads -> 8 lanes cover all 32 banks
// per phase (structural 8-phase floor). LDS 76KB -> 2 blocks/CU.
// ---------------------------------------------------------------------------
__global__ __launch_bounds__(256) void pair_kernel(
    const int* __restrict__ S1, const int* __restrict__ S2,
    const float* __restrict__ contact,
    const float* __restrict__ P1, const float* __restrict__ P2,
    const float* __restrict__ W2, const float* __restrict__ b2,
    float* __restrict__ out)
{
    const int NT = 16, MT = 128;
    const int nTn = (N1_ + NT - 1) / NT;    // 32
    const int nTm = (N2_ + MT - 1) / MT;    // 7
    int bid = blockIdx.x;
    int tb  = bid / (nTn * nTm);
    int rem = bid % (nTn * nTm);
    int tn  = rem / nTm;
    int tm  = rem % nTm;
    int n0 = tn * NT, m0 = tm * MT;
    int tid = threadIdx.x, lane = tid & 63, wave = tid >> 6;
    bool fullTile = (m0 + MT <= N2_);       // block-uniform

    __shared__ float p2s[128 * 132];  // 67.6 KB, padded stride
    __shared__ float p1s[16 * 128];   // 8 KB
    __shared__ float w2s[128];
    __shared__ float m1s[16];

    // stage P2 tile (128 rows x 128 floats; guarded tail rows -> 0)
    const float* __restrict__ P2b = P2 + ((size_t)tb * N2_ + m0) * D_;
    #pragma unroll
    for (int j = 0; j < 16; ++j) {
        int fi  = tid + j * 256;      // 4096 float4s
        int row = fi >> 5;
        int c4  = (fi & 31) * 4;
        float4 v = make_float4(0.f, 0.f, 0.f, 0.f);
        if (m0 + row < N2_) v = *reinterpret_cast<const float4*>(&P2b[row * D_ + c4]);
        *reinterpret_cast<float4*>(&p2s[row * 132 + c4]) = v;
    }
    // stage P1 tile
    const float* __restrict__ P1b = P1 + ((size_t)tb * N1_ + n0) * D_;
    #pragma unroll
    for (int j = 0; j < 2; ++j) {
        int fi  = tid + j * 256;
        int row = fi >> 5;
        int c4  = (fi & 31) * 4;
        float4 v = make_float4(0.f, 0.f, 0.f, 0.f);
        if (n0 + row < N1_) v = *reinterpret_cast<const float4*>(&P1b[row * D_ + c4]);
        *reinterpret_cast<float4*>(&p1s[row * 128 + c4]) = v;
    }
    if (tid < 32)
        *reinterpret_cast<float4*>(&w2s[tid * 4]) =
            *reinterpret_cast<const float4*>(&W2[tid * 4]);
    if (tid >= 64 && tid < 80) {
        int i = tid - 64;
        m1s[i] = (n0 + i < N1_ && S1[tb * N1_ + n0 + i] != 0) ? 1.f : 0.f;
    }
    // hoist epilogue globals before the barrier to overlap latency
    int mA = m0 + lane;
    int mB = m0 + 64 + lane;
    float m2A = (mA < N2_ && S2[tb * N2_ + mA] != 0) ? 1.f : 0.f;
    float m2B = (fullTile && S2[tb * N2_ + mB] != 0) ? 1.f : 0.f;
    float bias2 = b2[0];
    __syncthreads();

    int nw = wave * 4;
    float acc0[4] = {0.f, 0.f, 0.f, 0.f};
    float acc1[4] = {0.f, 0.f, 0.f, 0.f};
    const float* p2a = &p2s[lane * 132];
    const float* p2b = &p2s[(lane + 64) * 132];
    const float* p1p = &p1s[nw * 128];

    if (fullTile) {
        #pragma unroll 4
        for (int d = 0; d < D_; d += 4) {
            float4 qa = *reinterpret_cast<const float4*>(&p2a[d]);
            float4 qb = *reinterpret_cast<const float4*>(&p2b[d]);
            float4 w  = *reinterpret_cast<const float4*>(&w2s[d]);
            #pragma unroll
            for (int i = 0; i < 4; ++i) {
                float4 q1 = *reinterpret_cast<const float4*>(&p1p[i * 128 + d]);
                acc0[i] = fmaf(fmaxf(q1.x + qa.x, 0.f), w.x, acc0[i]);
                acc0[i] = fmaf(fmaxf(q1.y + qa.y, 0.f), w.y, acc0[i]);
                acc0[i] = fmaf(fmaxf(q1.z + qa.z, 0.f), w.z, acc0[i]);
                acc0[i] = fmaf(fmaxf(q1.w + qa.w, 0.f), w.w, acc0[i]);
                acc1[i] = fmaf(fmaxf(q1.x + qb.x, 0.f), w.x, acc1[i]);
                acc1[i] = fmaf(fmaxf(q1.y + qb.y, 0.f), w.y, acc1[i]);
                acc1[i] = fmaf(fmaxf(q1.z + qb.z, 0.f), w.z, acc1[i]);
                acc1[i] = fmaf(fmaxf(q1.w + qb.w, 0.f), w.w, acc1[i]);
            }
        }
    } else {
        // tail tile: only columns [m0, N2) exist; single-column path
        #pragma unroll 4
        for (int d = 0; d < D_; d += 4) {
            float4 qa = *reinterpret_cast<const float4*>(&p2a[d]);
            float4 w  = *reinterpret_cast<const float4*>(&w2s[d]);
            #pragma unroll
            for (int i = 0; i < 4; ++i) {
                float4 q1 = *reinterpret_cast<const float4*>(&p1p[i * 128 + d]);
                acc0[i] = fmaf(fmaxf(q1.x + qa.x, 0.f), w.x, acc0[i]);
                acc0[i] = fmaf(fmaxf(q1.y + qa.y, 0.f), w.y, acc0[i]);
                acc0[i] = fmaf(fmaxf(q1.z + qa.z, 0.f), w.z, acc0[i]);
                acc0[i] = fmaf(fmaxf(q1.w + qa.w, 0.f), w.w, acc0[i]);
            }
        }
    }

    // fused epilogue: pred (unmasked), y_contact, mask — coalesced along m
    const size_t NN  = (size_t)N1_ * N2_;   // 400000
    const size_t TOT = (size_t)B_ * NN;     // 800000
    #pragma unroll
    for (int i = 0; i < 4; ++i) {
        int n = n0 + nw + i;
        if (n >= N1_) break;
        float m1v = m1s[nw + i];
        size_t rowoff = (size_t)tb * NN + (size_t)n * N2_;
        if (mA < N2_) {
            float mk = m1v * m2A;
            size_t off = rowoff + mA;
            float cv = contact[off];
            out[off]           = acc0[i] + bias2;
            out[TOT + off]     = (cv < 0.5f) ? mk : 0.f;
            out[2 * TOT + off] = mk;
        }
        if (fullTile) {
            float mk = m1v * m2B;
            size_t off = rowoff + mB;
            float cv = contact[off];
            out[off]           = acc1[i] + bias2;
            out[TOT + off]     = (cv < 0.5f) ? mk : 0.f;
            out[2 * TOT + off] = mk;
        }
    }
}

extern "C" void kernel_launch(void* const* d_in, const int* in_sizes, int n_in,
                              void* d_out, int out_size, void* d_ws, size_t ws_size,
                              hipStream_t stream) {
    const int*   S1      = (const int*)d_in[0];
    const int*   S2      = (const int*)d_in[1];
    const float* h1      = (const float*)d_in[2];
    const float* h2      = (const float*)d_in[3];
    const float* contact = (const float*)d_in[4];
    const float* W1      = (const float*)d_in[5];
    const float* b1      = (const float*)d_in[6];
    const float* W2      = (const float*)d_in[7];
    const float* b2      = (const float*)d_in[8];
    float* out = (float*)d_out;

    float* P1 = (float*)d_ws;                         // B*N1*D floats
    float* P2 = P1 + (size_t)B_ * N1_ * D_;           // B*N2*D floats

    const int projBlocks = (B_ * N1_ + 7) / 8 + (B_ * N2_) / 8;  // 125 + 200
    proj_kernel<<<projBlocks, 256, 0, stream>>>(h1, h2, W1, b1, P1, P2);

    const int pairBlocks = B_ * ((N1_ + 15) / 16) * ((N2_ + 127) / 128); // 448
    pair_kernel<<<pairBlocks, 256, 0, stream>>>(S1, S2, contact, P1, P2, W2, b2, out);
}